// Round 3
// baseline (1524.923 us; speedup 1.0000x reference)
//
#include <hip/hip_runtime.h>

// Problem constants
#define SEQ   2048
#define NHEAD 16
#define NKV   4
#define HDIM  128
#define NB    4
// qkv_raw row layout: [qg 0..4095 | k 4096..4607 | v 4608..5119]
#define QKVW  5120

typedef unsigned short u16;
typedef unsigned int   u32;
typedef __bf16 v8bf __attribute__((ext_vector_type(8)));
typedef float  v4f  __attribute__((ext_vector_type(4)));

__device__ __forceinline__ u16 f2bf(float f) {
  u32 u = __float_as_uint(f);
  u += 0x7fffu + ((u >> 16) & 1u);
  return (u16)(u >> 16);
}
__device__ __forceinline__ float bf2f(u16 b) {
  return __uint_as_float(((u32)b) << 16);
}

// ---------------------------------------------------------------------------
// fp32 -> bf16 bulk convert (8 elems/thread)
__global__ __launch_bounds__(256) void conv_f32_bf16(const float* __restrict__ s,
                                                     u16* __restrict__ d) {
  size_t i = ((size_t)blockIdx.x * 256 + threadIdx.x) * 8;
  float4 a = *(const float4*)(s + i);
  float4 b = *(const float4*)(s + i + 4);
  uint4 o;
  o.x = (u32)f2bf(a.x) | ((u32)f2bf(a.y) << 16);
  o.y = (u32)f2bf(a.z) | ((u32)f2bf(a.w) << 16);
  o.z = (u32)f2bf(b.x) | ((u32)f2bf(b.y) << 16);
  o.w = (u32)f2bf(b.z) | ((u32)f2bf(b.w) << 16);
  *(uint4*)(d + i) = o;
}

// ---------------------------------------------------------------------------
// fp32 source -> bf16 transposed dst: dst[c*R + r] = bf16(src[r*C + c])
// grid (C/64, R/64), block 256. Tile stride 80 u16 = 160 B (16B-aligned rows).
__global__ __launch_bounds__(256) void transpose_w(const float* __restrict__ src,
                                                   u16* __restrict__ dst,
                                                   int R, int C) {
  __shared__ u16 tile[64][80];
  int t = threadIdx.x;
  int r0 = blockIdx.y * 64, c0 = blockIdx.x * 64;
  int rr = t >> 2, cc = (t & 3) * 16;
  const float* sp = src + (size_t)(r0 + rr) * C + c0 + cc;
  float4 f0 = *(const float4*)sp;
  float4 f1 = *(const float4*)(sp + 4);
  float4 f2 = *(const float4*)(sp + 8);
  float4 f3 = *(const float4*)(sp + 12);
  u16* tp = &tile[rr][cc];
  tp[0] = f2bf(f0.x);  tp[1] = f2bf(f0.y);  tp[2] = f2bf(f0.z);  tp[3] = f2bf(f0.w);
  tp[4] = f2bf(f1.x);  tp[5] = f2bf(f1.y);  tp[6] = f2bf(f1.z);  tp[7] = f2bf(f1.w);
  tp[8] = f2bf(f2.x);  tp[9] = f2bf(f2.y);  tp[10] = f2bf(f2.z); tp[11] = f2bf(f2.w);
  tp[12] = f2bf(f3.x); tp[13] = f2bf(f3.y); tp[14] = f2bf(f3.z); tp[15] = f2bf(f3.w);
  __syncthreads();
  int cr = t >> 2, rc = (t & 3) * 16;
  u32 pk[8];
#pragma unroll
  for (int i = 0; i < 8; i++) {
    u32 lo = tile[rc + 2 * i][cr];
    u32 hi = tile[rc + 2 * i + 1][cr];
    pk[i] = lo | (hi << 16);
  }
  u16* dp = dst + (size_t)(c0 + cr) * R + r0 + rc;
  uint4 o0 = {pk[0], pk[1], pk[2], pk[3]};
  uint4 o1 = {pk[4], pk[5], pk[6], pk[7]};
  *(uint4*)dp       = o0;
  *(uint4*)(dp + 8) = o1;
}

// ---------------------------------------------------------------------------
// V transpose (bf16->bf16): vt[((b*NKV+g)*HDIM + d)*SEQ + s] =
//   qkv[(b*SEQ+s)*QKVW + 4608 + g*HDIM + d]
// grid (SEQ/64, HDIM/64, NB*NKV), block 256
__global__ __launch_bounds__(256) void transpose_v(const u16* __restrict__ qkv,
                                                   u16* __restrict__ vt) {
  __shared__ u16 tile[64][80];
  int t = threadIdx.x;
  int s0 = blockIdx.x * 64;
  int d0 = blockIdx.y * 64;
  int bg = blockIdx.z;
  int b = bg >> 2, g = bg & 3;
  int sr = t >> 2, dc = (t & 3) * 16;
  const u16* sp = qkv + (size_t)(b * SEQ + s0 + sr) * QKVW + 4608 + g * HDIM + d0 + dc;
  *(uint4*)&tile[sr][dc]     = *(const uint4*)sp;
  *(uint4*)&tile[sr][dc + 8] = *(const uint4*)(sp + 8);
  __syncthreads();
  int dr = t >> 2, sc = (t & 3) * 16;
  u32 pk[8];
#pragma unroll
  for (int i = 0; i < 8; i++) {
    u32 lo = tile[sc + 2 * i][dr];
    u32 hi = tile[sc + 2 * i + 1][dr];
    pk[i] = lo | (hi << 16);
  }
  u16* dp = vt + ((size_t)bg * HDIM + d0 + dr) * SEQ + s0 + sc;
  uint4 o0 = {pk[0], pk[1], pk[2], pk[3]};
  uint4 o1 = {pk[4], pk[5], pk[6], pk[7]};
  *(uint4*)dp       = o0;
  *(uint4*)(dp + 8) = o1;
}

// ---------------------------------------------------------------------------
// GEMM: C[M,N] = A[M,K] * Bt[N,K]^T, bf16 in, fp32 accum.
// 128x128 block tile, 4 waves (2x2 of 64x64), MFMA 16x16x32_bf16, BK=32.
// grid (N/128, M/128), block 256. OUT_F32: store float C, else bf16 C.
template <bool OUT_F32>
__global__ __launch_bounds__(256) void gemm_bt(const u16* __restrict__ A,
                                               const u16* __restrict__ Bt,
                                               void* __restrict__ Cp,
                                               int M, int N, int K) {
  __shared__ u16 As[128 * 40];  // row stride 40 u16 = 80B (16B-aligned rows)
  __shared__ u16 Bs[128 * 40];
  int tid  = threadIdx.x;
  int lane = tid & 63, wave = tid >> 6;
  int wr = wave >> 1, wc = wave & 1;
  int col = lane & 15, quad = lane >> 4;
  int m0 = blockIdx.y * 128, n0 = blockIdx.x * 128;

  v4f acc[4][4];
#pragma unroll
  for (int mi = 0; mi < 4; mi++)
#pragma unroll
    for (int ni = 0; ni < 4; ni++) acc[mi][ni] = (v4f){0.f, 0.f, 0.f, 0.f};

  int srow = tid >> 2;            // 0..63
  int skc  = (tid & 3) * 8;       // 0,8,16,24

  for (int k0 = 0; k0 < K; k0 += 32) {
    __syncthreads();
    *(uint4*)&As[srow * 40 + skc] = *(const uint4*)&A[(size_t)(m0 + srow) * K + k0 + skc];
    *(uint4*)&Bs[srow * 40 + skc] = *(const uint4*)&Bt[(size_t)(n0 + srow) * K + k0 + skc];
    int srow2 = srow + 64;
    *(uint4*)&As[srow2 * 40 + skc] = *(const uint4*)&A[(size_t)(m0 + srow2) * K + k0 + skc];
    *(uint4*)&Bs[srow2 * 40 + skc] = *(const uint4*)&Bt[(size_t)(n0 + srow2) * K + k0 + skc];
    __syncthreads();

    v8bf a[4], bb[4];
#pragma unroll
    for (int mi = 0; mi < 4; mi++)
      a[mi] = *(const v8bf*)&As[(wr * 64 + mi * 16 + col) * 40 + quad * 8];
#pragma unroll
    for (int ni = 0; ni < 4; ni++)
      bb[ni] = *(const v8bf*)&Bs[(wc * 64 + ni * 16 + col) * 40 + quad * 8];
#pragma unroll
    for (int mi = 0; mi < 4; mi++)
#pragma unroll
      for (int ni = 0; ni < 4; ni++)
        acc[mi][ni] = __builtin_amdgcn_mfma_f32_16x16x32_bf16(a[mi], bb[ni], acc[mi][ni], 0, 0, 0);
  }

  // epilogue: C/D layout row = quad*4+reg, col = lane&15
#pragma unroll
  for (int mi = 0; mi < 4; mi++)
#pragma unroll
    for (int ni = 0; ni < 4; ni++) {
      int r_ = m0 + wr * 64 + mi * 16 + quad * 4;
      int c_ = n0 + wc * 64 + ni * 16 + col;
#pragma unroll
      for (int r = 0; r < 4; r++) {
        if (OUT_F32) ((float*)Cp)[(size_t)(r_ + r) * N + c_] = acc[mi][ni][r];
        else         ((u16*)Cp)[(size_t)(r_ + r) * N + c_]   = f2bf(acc[mi][ni][r]);
      }
    }
}

// ---------------------------------------------------------------------------
// RMS-norm (+ 1+w) + RoPE on q and k head-rows, IN PLACE in qkv_raw.
// cos/sin/norm-weights read as fp32. One wave per (token, head-row).
// grid (NB*SEQ*(NHEAD+NKV)/4), block 256
__global__ __launch_bounds__(256) void norm_rope(u16* __restrict__ qkv,
                                                 const float* __restrict__ cosb,
                                                 const float* __restrict__ sinb,
                                                 const float* __restrict__ qw,
                                                 const float* __restrict__ kw) {
  int wave = threadIdx.x >> 6, lane = threadIdx.x & 63;
  int tw = blockIdx.x * 4 + wave;
  int token = tw / 20, r = tw % 20;
  u16* ptr;
  const float* wptr;
  if (r < 16) {
    ptr  = qkv + (size_t)token * QKVW + r * 256;       // q of head r (cols 0..127)
    wptr = qw;
  } else {
    ptr  = qkv + (size_t)token * QKVW + 4096 + (r - 16) * HDIM;
    wptr = kw;
  }
  int d0 = lane * 2;
  u32 x = *(const u32*)(ptr + d0);
  float x0 = bf2f((u16)(x & 0xffff)), x1 = bf2f((u16)(x >> 16));
  float ss = x0 * x0 + x1 * x1;
#pragma unroll
  for (int off = 1; off < 64; off <<= 1) ss += __shfl_xor(ss, off, 64);
  float sc = rsqrtf(ss * (1.f / 128.f) + 1e-6f);
  // bf16-round the normed value (needed as MFMA input anyway)
  float y0 = bf2f(f2bf(x0 * sc * (1.f + wptr[d0])));
  float y1 = bf2f(f2bf(x1 * sc * (1.f + wptr[d0 + 1])));
  float p0 = __shfl_xor(y0, 8, 64);  // rope partner at d +/- 16
  float p1 = __shfl_xor(y1, 8, 64);
  float z0 = y0, z1 = y1;
  if (lane < 16) {  // rotary dims d < 32
    float c0 = cosb[(size_t)token * 32 + d0];
    float c1 = cosb[(size_t)token * 32 + d0 + 1];
    float s0 = sinb[(size_t)token * 32 + d0];
    float s1 = sinb[(size_t)token * 32 + d0 + 1];
    if (lane < 8) { z0 = y0 * c0 - p0 * s0; z1 = y1 * c1 - p1 * s1; }
    else          { z0 = y0 * c0 + p0 * s0; z1 = y1 * c1 + p1 * s1; }
  }
  u32 outp = (u32)f2bf(z0) | ((u32)f2bf(z1) << 16);
  *(u32*)(ptr + d0) = outp;
}

// ---------------------------------------------------------------------------
// Causal GQA flash attention + sigmoid-gate epilogue.
// q,k read in place from qkv_raw; v from vt (d-major); out bf16 to ga.
// grid (SEQ/64, NHEAD, NB), block 256 (4 waves, each owns 16 q rows)
__global__ __launch_bounds__(256) void attn_kernel(const u16* __restrict__ qkv,
                                                   const u16* __restrict__ vt,
                                                   u16* __restrict__ ga) {
  __shared__ u16 plds[4][16 * 40];  // per-wave P tile (16 q rows x 32 kv)
  int tid = threadIdx.x, lane = tid & 63, wave = tid >> 6;
  int col = lane & 15, quad = lane >> 4;
  int qt = blockIdx.x, h = blockIdx.y, b = blockIdx.z;
  int g = h >> 2;
  int qw0 = qt * 64 + wave * 16;
  const float scl = 0.08838834764831845f;  // D^-0.5

  // Q fragments (A-layout: m = lane&15, k = quad*8+j), 4 chunks of K=32
  v8bf qfr[4];
  const u16* qbase = qkv + (size_t)(b * SEQ + qw0 + col) * QKVW + h * 256 + quad * 8;
#pragma unroll
  for (int kc = 0; kc < 4; kc++) qfr[kc] = *(const v8bf*)(qbase + kc * 32);

  v4f o[8];
#pragma unroll
  for (int nt = 0; nt < 8; nt++) o[nt] = (v4f){0.f, 0.f, 0.f, 0.f};
  float m4[4], l4[4];
#pragma unroll
  for (int r = 0; r < 4; r++) { m4[r] = -1e30f; l4[r] = 0.f; }

  int kend = qt * 64 + 64;  // uniform trip count across waves
  for (int k0 = 0; k0 < kend; k0 += 32) {
    // --- S = Q K^T ---
    v4f st[2];
#pragma unroll
    for (int t = 0; t < 2; t++) {
      v4f acc = (v4f){0.f, 0.f, 0.f, 0.f};
      const u16* kbase = qkv + (size_t)(b * SEQ + k0 + t * 16 + col) * QKVW + 4096 + g * HDIM + quad * 8;
#pragma unroll
      for (int kc = 0; kc < 4; kc++) {
        v8bf kfr = *(const v8bf*)(kbase + kc * 32);
        acc = __builtin_amdgcn_mfma_f32_16x16x32_bf16(qfr[kc], kfr, acc, 0, 0, 0);
      }
      st[t] = acc;
    }
    // --- online softmax (row = quad*4+r, col = lane&15 in tile) ---
    float alpha[4];
#pragma unroll
    for (int r = 0; r < 4; r++) {
      int qrow = qw0 + quad * 4 + r;
      float s0 = st[0][r] * scl; if (k0 + col > qrow)      s0 = -1e30f;
      float s1 = st[1][r] * scl; if (k0 + 16 + col > qrow) s1 = -1e30f;
      float mx = fmaxf(s0, s1);
      mx = fmaxf(mx, __shfl_xor(mx, 1, 16));
      mx = fmaxf(mx, __shfl_xor(mx, 2, 16));
      mx = fmaxf(mx, __shfl_xor(mx, 4, 16));
      mx = fmaxf(mx, __shfl_xor(mx, 8, 16));
      float nm = fmaxf(m4[r], mx);
      alpha[r] = expf(m4[r] - nm);
      float p0 = expf(s0 - nm), p1 = expf(s1 - nm);
      u16 pb0 = f2bf(p0), pb1 = f2bf(p1);  // probs as bf16 into PV MFMA
      plds[wave][(quad * 4 + r) * 40 + col]      = pb0;
      plds[wave][(quad * 4 + r) * 40 + 16 + col] = pb1;
      float pv = bf2f(pb0) + bf2f(pb1);
      pv += __shfl_xor(pv, 1, 16);
      pv += __shfl_xor(pv, 2, 16);
      pv += __shfl_xor(pv, 4, 16);
      pv += __shfl_xor(pv, 8, 16);
      l4[r] = l4[r] * alpha[r] + pv;
      m4[r] = nm;
    }
#pragma unroll
    for (int nt = 0; nt < 8; nt++)
#pragma unroll
      for (int r = 0; r < 4; r++) o[nt][r] *= alpha[r];
    __syncthreads();  // drains each wave's own LDS writes before reads
    // --- P V (P via LDS round-trip to A-layout; V d-major) ---
    v8bf pa = *(const v8bf*)&plds[wave][col * 40 + quad * 8];
    const u16* vbase = vt + ((size_t)(b * NKV + g) * HDIM + col) * SEQ + k0 + quad * 8;
#pragma unroll
    for (int nt = 0; nt < 8; nt++) {
      v8bf vb = *(const v8bf*)(vbase + (size_t)nt * 16 * SEQ);
      o[nt] = __builtin_amdgcn_mfma_f32_16x16x32_bf16(pa, vb, o[nt], 0, 0, 0);
    }
  }

  // --- epilogue: normalize, sigmoid-gate, store bf16 ---
#pragma unroll
  for (int nt = 0; nt < 8; nt++) {
#pragma unroll
    for (int r = 0; r < 4; r++) {
      int q = qw0 + quad * 4 + r;
      int d = nt * 16 + col;
      float av = o[nt][r] / l4[r];
      float gt = bf2f(qkv[(size_t)(b * SEQ + q) * QKVW + h * 256 + 128 + d]);
      float sg = 1.f / (1.f + expf(-gt));
      ga[(size_t)(b * SEQ + q) * 2048 + h * HDIM + d] = f2bf(av * sg);
    }
  }
}

// ---------------------------------------------------------------------------
extern "C" void kernel_launch(void* const* d_in, const int* in_sizes, int n_in,
                              void* d_out, int out_size, void* d_ws, size_t ws_size,
                              hipStream_t stream) {
  const float* hidden = (const float*)d_in[0];
  const float* cosb   = (const float*)d_in[1];
  const float* sinb   = (const float*)d_in[2];
  // d_in[3] attention_mask: exact causal triu(-1e9) -> applied analytically
  const float* wq  = (const float*)d_in[4];
  const float* wk  = (const float*)d_in[5];
  const float* wv  = (const float*)d_in[6];
  const float* wo  = (const float*)d_in[7];
  const float* qnw = (const float*)d_in[8];
  const float* knw = (const float*)d_in[9];
  float* out = (float*)d_out;

  // Workspace (u16 units), time-aliased:
  //  region1: qkv_raw           8192*5120            (live: gemm_qkv .. attn)
  //  region2: hidden_bf         8192*2048            (live: conv .. gemm_qkv)
  //           g_attn  (alias)   8192*2048            (live: attn .. gemm_out)
  //  region3: bt_qkv            5120*2048            (live: transpose .. gemm_qkv)
  //           vt      (alias)   NB*NKV*HDIM*SEQ = 4M (live: transpose_v .. attn)
  //           bt_wo   (alias+4M)2048*2048            (live: transpose_wo .. gemm_out)
  // total 69,206,016 u16 = 138.4 MB
  u16* ws      = (u16*)d_ws;
  u16* qkv_raw = ws;
  u16* region2 = qkv_raw + (size_t)8192 * QKVW;
  u16* region3 = region2 + (size_t)8192 * 2048;
  u16* hidden_bf = region2;
  u16* g_attn    = region2;
  u16* bt_qkv    = region3;
  u16* vt        = region3;
  u16* bt_wo     = region3 + (size_t)NB * NKV * HDIM * SEQ;

  // 1) convert hidden fp32 -> bf16
  conv_f32_bf16<<<dim3(8192), 256, 0, stream>>>(hidden, hidden_bf);
  // 2) convert+transpose qkv weights into B^T bf16 (wq|wk|wv row-concat)
  transpose_w<<<dim3(64, 32), 256, 0, stream>>>(wq, bt_qkv, 2048, 4096);
  transpose_w<<<dim3(8, 32), 256, 0, stream>>>(wk, bt_qkv + (size_t)4096 * 2048, 2048, 512);
  transpose_w<<<dim3(8, 32), 256, 0, stream>>>(wv, bt_qkv + (size_t)4608 * 2048, 2048, 512);
  // 3) fused QKV projection (bf16 out)
  gemm_bt<false><<<dim3(QKVW / 128, 8192 / 128), 256, 0, stream>>>(hidden_bf, bt_qkv, qkv_raw, 8192, QKVW, 2048);
  // 4) RMS-norm + RoPE in place (q, k)
  norm_rope<<<dim3(8192 * 20 / 4), 256, 0, stream>>>(qkv_raw, cosb, sinb, qnw, knw);
  // 5) V -> d-major (overwrites bt_qkv, now dead)
  transpose_v<<<dim3(SEQ / 64, HDIM / 64, NB * NKV), 256, 0, stream>>>(qkv_raw, vt);
  // 6) convert+transpose wo (into region3 past vt)
  transpose_w<<<dim3(32, 32), 256, 0, stream>>>(wo, bt_wo, 2048, 2048);
  // 7) causal flash attention + gating (writes g_attn over dead hidden_bf)
  attn_kernel<<<dim3(SEQ / 64, NHEAD, NB), 256, 0, stream>>>(qkv_raw, vt, g_attn);
  // 8) output projection, fp32 store
  gemm_bt<true><<<dim3(2048 / 128, 8192 / 128), 256, 0, stream>>>(g_attn, bt_wo, out, 8192, 2048, 2048);
}

// Round 4
// 902.958 us; speedup vs baseline: 1.6888x; 1.6888x over previous
//
#include <hip/hip_runtime.h>

// Problem constants
#define SEQ   2048
#define NHEAD 16
#define NKV   4
#define HDIM  128
#define NB    4
// qkv_raw row layout: [qg 0..4095 | k 4096..4607 | v 4608..5119]
#define QKVW  5120

typedef unsigned short u16;
typedef unsigned int   u32;
typedef __bf16 v8bf __attribute__((ext_vector_type(8)));
typedef float  v4f  __attribute__((ext_vector_type(4)));

__device__ __forceinline__ u16 f2bf(float f) {
  u32 u = __float_as_uint(f);
  u += 0x7fffu + ((u >> 16) & 1u);
  return (u16)(u >> 16);
}
__device__ __forceinline__ float bf2f(u16 b) {
  return __uint_as_float(((u32)b) << 16);
}

// ---------------------------------------------------------------------------
// fp32 -> bf16 bulk convert (8 elems/thread)
__global__ __launch_bounds__(256) void conv_f32_bf16(const float* __restrict__ s,
                                                     u16* __restrict__ d) {
  size_t i = ((size_t)blockIdx.x * 256 + threadIdx.x) * 8;
  float4 a = *(const float4*)(s + i);
  float4 b = *(const float4*)(s + i + 4);
  uint4 o;
  o.x = (u32)f2bf(a.x) | ((u32)f2bf(a.y) << 16);
  o.y = (u32)f2bf(a.z) | ((u32)f2bf(a.w) << 16);
  o.z = (u32)f2bf(b.x) | ((u32)f2bf(b.y) << 16);
  o.w = (u32)f2bf(b.z) | ((u32)f2bf(b.w) << 16);
  *(uint4*)(d + i) = o;
}

// ---------------------------------------------------------------------------
// fp32 source -> bf16 transposed dst: dst[c*R + r] = bf16(src[r*C + c])
// grid (C/64, R/64), block 256. Tile stride 80 u16 = 160 B (16B-aligned rows).
__global__ __launch_bounds__(256) void transpose_w(const float* __restrict__ src,
                                                   u16* __restrict__ dst,
                                                   int R, int C) {
  __shared__ u16 tile[64][80];
  int t = threadIdx.x;
  int r0 = blockIdx.y * 64, c0 = blockIdx.x * 64;
  int rr = t >> 2, cc = (t & 3) * 16;
  const float* sp = src + (size_t)(r0 + rr) * C + c0 + cc;
  float4 f0 = *(const float4*)sp;
  float4 f1 = *(const float4*)(sp + 4);
  float4 f2 = *(const float4*)(sp + 8);
  float4 f3 = *(const float4*)(sp + 12);
  u16* tp = &tile[rr][cc];
  tp[0] = f2bf(f0.x);  tp[1] = f2bf(f0.y);  tp[2] = f2bf(f0.z);  tp[3] = f2bf(f0.w);
  tp[4] = f2bf(f1.x);  tp[5] = f2bf(f1.y);  tp[6] = f2bf(f1.z);  tp[7] = f2bf(f1.w);
  tp[8] = f2bf(f2.x);  tp[9] = f2bf(f2.y);  tp[10] = f2bf(f2.z); tp[11] = f2bf(f2.w);
  tp[12] = f2bf(f3.x); tp[13] = f2bf(f3.y); tp[14] = f2bf(f3.z); tp[15] = f2bf(f3.w);
  __syncthreads();
  int cr = t >> 2, rc = (t & 3) * 16;
  u32 pk[8];
#pragma unroll
  for (int i = 0; i < 8; i++) {
    u32 lo = tile[rc + 2 * i][cr];
    u32 hi = tile[rc + 2 * i + 1][cr];
    pk[i] = lo | (hi << 16);
  }
  u16* dp = dst + (size_t)(c0 + cr) * R + r0 + rc;
  uint4 o0 = {pk[0], pk[1], pk[2], pk[3]};
  uint4 o1 = {pk[4], pk[5], pk[6], pk[7]};
  *(uint4*)dp       = o0;
  *(uint4*)(dp + 8) = o1;
}

// ---------------------------------------------------------------------------
// V transpose (bf16->bf16): vt[((b*NKV+g)*HDIM + d)*SEQ + s] =
//   qkv[(b*SEQ+s)*QKVW + 4608 + g*HDIM + d]
// grid (SEQ/64, HDIM/64, NB*NKV), block 256
__global__ __launch_bounds__(256) void transpose_v(const u16* __restrict__ qkv,
                                                   u16* __restrict__ vt) {
  __shared__ u16 tile[64][80];
  int t = threadIdx.x;
  int s0 = blockIdx.x * 64;
  int d0 = blockIdx.y * 64;
  int bg = blockIdx.z;
  int b = bg >> 2, g = bg & 3;
  int sr = t >> 2, dc = (t & 3) * 16;
  const u16* sp = qkv + (size_t)(b * SEQ + s0 + sr) * QKVW + 4608 + g * HDIM + d0 + dc;
  *(uint4*)&tile[sr][dc]     = *(const uint4*)sp;
  *(uint4*)&tile[sr][dc + 8] = *(const uint4*)(sp + 8);
  __syncthreads();
  int dr = t >> 2, sc = (t & 3) * 16;
  u32 pk[8];
#pragma unroll
  for (int i = 0; i < 8; i++) {
    u32 lo = tile[sc + 2 * i][dr];
    u32 hi = tile[sc + 2 * i + 1][dr];
    pk[i] = lo | (hi << 16);
  }
  u16* dp = vt + ((size_t)bg * HDIM + d0 + dr) * SEQ + s0 + sc;
  uint4 o0 = {pk[0], pk[1], pk[2], pk[3]};
  uint4 o1 = {pk[4], pk[5], pk[6], pk[7]};
  *(uint4*)dp       = o0;
  *(uint4*)(dp + 8) = o1;
}

// ---------------------------------------------------------------------------
// GEMM: C[M,N] = A[M,K] * Bt[N,K]^T, bf16 in, fp32 accum.
// 128x128 block tile, 4 waves (2x2 of 64x64), MFMA 16x16x32_bf16, BK=32.
// grid (N/128, M/128), block 256. OUT_F32: store float C, else bf16 C.
template <bool OUT_F32>
__global__ __launch_bounds__(256) void gemm_bt(const u16* __restrict__ A,
                                               const u16* __restrict__ Bt,
                                               void* __restrict__ Cp,
                                               int M, int N, int K) {
  __shared__ u16 As[128 * 40];  // row stride 40 u16 = 80B (16B-aligned rows)
  __shared__ u16 Bs[128 * 40];
  int tid  = threadIdx.x;
  int lane = tid & 63, wave = tid >> 6;
  int wr = wave >> 1, wc = wave & 1;
  int col = lane & 15, quad = lane >> 4;
  int m0 = blockIdx.y * 128, n0 = blockIdx.x * 128;

  v4f acc[4][4];
#pragma unroll
  for (int mi = 0; mi < 4; mi++)
#pragma unroll
    for (int ni = 0; ni < 4; ni++) acc[mi][ni] = (v4f){0.f, 0.f, 0.f, 0.f};

  int srow = tid >> 2;            // 0..63
  int skc  = (tid & 3) * 8;       // 0,8,16,24

  for (int k0 = 0; k0 < K; k0 += 32) {
    __syncthreads();
    *(uint4*)&As[srow * 40 + skc] = *(const uint4*)&A[(size_t)(m0 + srow) * K + k0 + skc];
    *(uint4*)&Bs[srow * 40 + skc] = *(const uint4*)&Bt[(size_t)(n0 + srow) * K + k0 + skc];
    int srow2 = srow + 64;
    *(uint4*)&As[srow2 * 40 + skc] = *(const uint4*)&A[(size_t)(m0 + srow2) * K + k0 + skc];
    *(uint4*)&Bs[srow2 * 40 + skc] = *(const uint4*)&Bt[(size_t)(n0 + srow2) * K + k0 + skc];
    __syncthreads();

    v8bf a[4], bb[4];
#pragma unroll
    for (int mi = 0; mi < 4; mi++)
      a[mi] = *(const v8bf*)&As[(wr * 64 + mi * 16 + col) * 40 + quad * 8];
#pragma unroll
    for (int ni = 0; ni < 4; ni++)
      bb[ni] = *(const v8bf*)&Bs[(wc * 64 + ni * 16 + col) * 40 + quad * 8];
#pragma unroll
    for (int mi = 0; mi < 4; mi++)
#pragma unroll
      for (int ni = 0; ni < 4; ni++)
        acc[mi][ni] = __builtin_amdgcn_mfma_f32_16x16x32_bf16(a[mi], bb[ni], acc[mi][ni], 0, 0, 0);
  }

  // epilogue: C/D layout row = quad*4+reg, col = lane&15
#pragma unroll
  for (int mi = 0; mi < 4; mi++)
#pragma unroll
    for (int ni = 0; ni < 4; ni++) {
      int r_ = m0 + wr * 64 + mi * 16 + quad * 4;
      int c_ = n0 + wc * 64 + ni * 16 + col;
#pragma unroll
      for (int r = 0; r < 4; r++) {
        if (OUT_F32) ((float*)Cp)[(size_t)(r_ + r) * N + c_] = acc[mi][ni][r];
        else         ((u16*)Cp)[(size_t)(r_ + r) * N + c_]   = f2bf(acc[mi][ni][r]);
      }
    }
}

// ---------------------------------------------------------------------------
// RMS-norm (+ 1+w) + RoPE. q normed IN PLACE in qkv_raw; k written to
// head-major kf[((b*NKV+g)*SEQ + s)*HDIM + d]. One wave per (token, head-row).
// grid (NB*SEQ*(NHEAD+NKV)/4), block 256
__global__ __launch_bounds__(256) void norm_rope(u16* __restrict__ qkv,
                                                 const float* __restrict__ cosb,
                                                 const float* __restrict__ sinb,
                                                 const float* __restrict__ qw,
                                                 const float* __restrict__ kw,
                                                 u16* __restrict__ kf) {
  int wave = threadIdx.x >> 6, lane = threadIdx.x & 63;
  int tw = blockIdx.x * 4 + wave;
  int token = tw / 20, r = tw % 20;
  const u16* src;
  u16* dst;
  const float* wptr;
  if (r < 16) {
    src  = qkv + (size_t)token * QKVW + r * 256;       // q of head r (cols 0..127)
    dst  = (u16*)src;                                  // in place
    wptr = qw;
  } else {
    src  = qkv + (size_t)token * QKVW + 4096 + (r - 16) * HDIM;
    int b = token >> 11, s = token & (SEQ - 1);
    dst  = kf + ((size_t)(b * NKV + (r - 16)) * SEQ + s) * HDIM;
    wptr = kw;
  }
  int d0 = lane * 2;
  u32 x = *(const u32*)(src + d0);
  float x0 = bf2f((u16)(x & 0xffff)), x1 = bf2f((u16)(x >> 16));
  float ss = x0 * x0 + x1 * x1;
#pragma unroll
  for (int off = 1; off < 64; off <<= 1) ss += __shfl_xor(ss, off, 64);
  float sc = rsqrtf(ss * (1.f / 128.f) + 1e-6f);
  float y0 = bf2f(f2bf(x0 * sc * (1.f + wptr[d0])));
  float y1 = bf2f(f2bf(x1 * sc * (1.f + wptr[d0 + 1])));
  float p0 = __shfl_xor(y0, 8, 64);  // rope partner at d +/- 16
  float p1 = __shfl_xor(y1, 8, 64);
  float z0 = y0, z1 = y1;
  if (lane < 16) {  // rotary dims d < 32
    float c0 = cosb[(size_t)token * 32 + d0];
    float c1 = cosb[(size_t)token * 32 + d0 + 1];
    float s0 = sinb[(size_t)token * 32 + d0];
    float s1 = sinb[(size_t)token * 32 + d0 + 1];
    if (lane < 8) { z0 = y0 * c0 - p0 * s0; z1 = y1 * c1 - p1 * s1; }
    else          { z0 = y0 * c0 + p0 * s0; z1 = y1 * c1 + p1 * s1; }
  }
  u32 outp = (u32)f2bf(z0) | ((u32)f2bf(z1) << 16);
  *(u32*)(dst + d0) = outp;
}

// ---------------------------------------------------------------------------
// Causal GQA flash attention + sigmoid-gate epilogue, LDS-staged K/V.
// Block: 64 q-rows, 4 waves x 16 rows. K-tile 64. exp2-domain softmax,
// row-sums via ones-MFMA. grid (32, NHEAD, NB), block 256.
__global__ __launch_bounds__(256) void attn_kernel(const u16* __restrict__ qkv,
                                                   const u16* __restrict__ kf,
                                                   const u16* __restrict__ vt,
                                                   u16* __restrict__ ga) {
  __shared__ u16 ks[64 * 136];      // K-tile s-major, stride 136 (272B rows)
  __shared__ u16 vs[128 * 88];      // V-tile d-major, stride 88 (176B rows)
  __shared__ u16 ps[4][16 * 88];    // per-wave P tile, stride 88
  int tid = threadIdx.x, lane = tid & 63, wave = tid >> 6;
  int col = lane & 15, quad = lane >> 4;
  int qt = 31 - blockIdx.x;         // heavy causal blocks dispatch first (LPT)
  int h = blockIdx.y, b = blockIdx.z;
  int g = h >> 2;
  int qw0 = qt * 64 + wave * 16;
  const float scl2 = 0.08838834764831845f * 1.4426950408889634f;  // D^-.5 * log2e

  // Q fragments (A-layout: m=lane&15, k=quad*8+j), once per block
  v8bf qfr[4];
  const u16* qbase = qkv + (size_t)(b * SEQ + qw0 + col) * QKVW + h * 256 + quad * 8;
#pragma unroll
  for (int kc = 0; kc < 4; kc++) qfr[kc] = *(const v8bf*)(qbase + kc * 32);

  v8bf ones;
#pragma unroll
  for (int i = 0; i < 8; i++) ones[i] = (__bf16)1.0f;

  v4f o[8];
#pragma unroll
  for (int nt = 0; nt < 8; nt++) o[nt] = (v4f){0.f, 0.f, 0.f, 0.f};
  v4f lacc = (v4f){0.f, 0.f, 0.f, 0.f};
  float m4[4];
#pragma unroll
  for (int r = 0; r < 4; r++) m4[r] = -1e30f;

  const u16* kfb = kf + (size_t)(b * NKV + g) * SEQ * HDIM;
  const u16* vtb = vt + (size_t)(b * NKV + g) * HDIM * SEQ;

  int ksr = tid >> 4, ksd = (tid & 15) * 8;   // K staging map
  int vsd = tid >> 3, vss = (tid & 7) * 8;    // V staging map

  int nk = qt + 1;
  for (int it = 0; it < nk; it++) {
    int k0 = it * 64;
    __syncthreads();  // previous iteration's LDS reads complete
#pragma unroll
    for (int p = 0; p < 4; p++)
      *(uint4*)&ks[(ksr + p * 16) * 136 + ksd] =
          *(const uint4*)&kfb[(size_t)(k0 + ksr + p * 16) * HDIM + ksd];
#pragma unroll
    for (int p = 0; p < 4; p++)
      *(uint4*)&vs[(vsd + p * 32) * 88 + vss] =
          *(const uint4*)&vtb[(size_t)(vsd + p * 32) * SEQ + k0 + vss];
    __syncthreads();

    // --- S = Q K^T over 4 col-tiles of 16 ---
    v4f st[4];
#pragma unroll
    for (int t = 0; t < 4; t++) {
      v4f acc = (v4f){0.f, 0.f, 0.f, 0.f};
#pragma unroll
      for (int kc = 0; kc < 4; kc++) {
        v8bf kfr = *(const v8bf*)&ks[(t * 16 + col) * 136 + kc * 32 + quad * 8];
        acc = __builtin_amdgcn_mfma_f32_16x16x32_bf16(qfr[kc], kfr, acc, 0, 0, 0);
      }
      st[t] = acc;
    }

    // --- online softmax (exp2 domain); row = quad*4+r, col-tile t, col ---
    bool diag = (it == nk - 1);
    float alpha[4];
#pragma unroll
    for (int r = 0; r < 4; r++) {
      int qrow = qw0 + quad * 4 + r;
      float sv[4];
#pragma unroll
      for (int t = 0; t < 4; t++) {
        sv[t] = st[t][r] * scl2;
        if (diag && (k0 + t * 16 + col > qrow)) sv[t] = -1e30f;
      }
      float mx = fmaxf(fmaxf(sv[0], sv[1]), fmaxf(sv[2], sv[3]));
      mx = fmaxf(mx, __shfl_xor(mx, 1, 16));
      mx = fmaxf(mx, __shfl_xor(mx, 2, 16));
      mx = fmaxf(mx, __shfl_xor(mx, 4, 16));
      mx = fmaxf(mx, __shfl_xor(mx, 8, 16));
      float nm = fmaxf(m4[r], mx);
      alpha[r] = exp2f(m4[r] - nm);
      m4[r] = nm;
#pragma unroll
      for (int t = 0; t < 4; t++) {
        u16 pb = f2bf(exp2f(sv[t] - nm));
        ps[wave][(quad * 4 + r) * 88 + t * 16 + col] = pb;
      }
    }
    // rescale accumulators
#pragma unroll
    for (int nt = 0; nt < 8; nt++)
#pragma unroll
      for (int r = 0; r < 4; r++) o[nt][r] *= alpha[r];
#pragma unroll
    for (int r = 0; r < 4; r++) lacc[r] *= alpha[r];

    // --- P V + row-sum via ones-MFMA (P per-wave LDS round-trip) ---
    v8bf pa0 = *(const v8bf*)&ps[wave][col * 88 + quad * 8];
    v8bf pa1 = *(const v8bf*)&ps[wave][col * 88 + 32 + quad * 8];
    lacc = __builtin_amdgcn_mfma_f32_16x16x32_bf16(pa0, ones, lacc, 0, 0, 0);
    lacc = __builtin_amdgcn_mfma_f32_16x16x32_bf16(pa1, ones, lacc, 0, 0, 0);
#pragma unroll
    for (int nt = 0; nt < 8; nt++) {
      v8bf vb0 = *(const v8bf*)&vs[(nt * 16 + col) * 88 + quad * 8];
      v8bf vb1 = *(const v8bf*)&vs[(nt * 16 + col) * 88 + 32 + quad * 8];
      o[nt] = __builtin_amdgcn_mfma_f32_16x16x32_bf16(pa0, vb0, o[nt], 0, 0, 0);
      o[nt] = __builtin_amdgcn_mfma_f32_16x16x32_bf16(pa1, vb1, o[nt], 0, 0, 0);
    }
  }

  // --- epilogue: normalize, sigmoid-gate, store bf16 ---
#pragma unroll
  for (int nt = 0; nt < 8; nt++) {
#pragma unroll
    for (int r = 0; r < 4; r++) {
      int q = qw0 + quad * 4 + r;
      int d = nt * 16 + col;
      float av = o[nt][r] / lacc[r];
      float gt = bf2f(qkv[(size_t)(b * SEQ + q) * QKVW + h * 256 + 128 + d]);
      float sg = 1.f / (1.f + expf(-gt));
      ga[(size_t)(b * SEQ + q) * 2048 + h * HDIM + d] = f2bf(av * sg);
    }
  }
}

// ---------------------------------------------------------------------------
extern "C" void kernel_launch(void* const* d_in, const int* in_sizes, int n_in,
                              void* d_out, int out_size, void* d_ws, size_t ws_size,
                              hipStream_t stream) {
  const float* hidden = (const float*)d_in[0];
  const float* cosb   = (const float*)d_in[1];
  const float* sinb   = (const float*)d_in[2];
  // d_in[3] attention_mask: exact causal triu(-1e9) -> applied analytically
  const float* wq  = (const float*)d_in[4];
  const float* wk  = (const float*)d_in[5];
  const float* wv  = (const float*)d_in[6];
  const float* wo  = (const float*)d_in[7];
  const float* qnw = (const float*)d_in[8];
  const float* knw = (const float*)d_in[9];
  float* out = (float*)d_out;

  // Workspace (u16 units), time-aliased:
  //  region1: qkv_raw 8192*5120                     41,943,040
  //  region2: hidden_bf | g_attn (alias) 8192*2048  16,777,216
  //  region3: bt_qkv 5120*2048 (dies after gemm_qkv)
  //           vt    (alias +0)      4,194,304
  //           bt_wo (alias +4.2M)   4,194,304
  //           k_f   (alias +8.4M)   4,194,304       region3 = 12,582,912
  // total 71,303,168 u16 = 142.6 MB
  u16* ws      = (u16*)d_ws;
  u16* qkv_raw = ws;
  u16* region2 = qkv_raw + (size_t)8192 * QKVW;
  u16* region3 = region2 + (size_t)8192 * 2048;
  u16* hidden_bf = region2;
  u16* g_attn    = region2;
  u16* bt_qkv    = region3;
  u16* vt        = region3;
  u16* bt_wo     = region3 + (size_t)4194304;
  u16* k_f       = region3 + (size_t)8388608;

  // 1) convert hidden fp32 -> bf16
  conv_f32_bf16<<<dim3(8192), 256, 0, stream>>>(hidden, hidden_bf);
  // 2) convert+transpose qkv weights into B^T bf16 (wq|wk|wv row-concat)
  transpose_w<<<dim3(64, 32), 256, 0, stream>>>(wq, bt_qkv, 2048, 4096);
  transpose_w<<<dim3(8, 32), 256, 0, stream>>>(wk, bt_qkv + (size_t)4096 * 2048, 2048, 512);
  transpose_w<<<dim3(8, 32), 256, 0, stream>>>(wv, bt_qkv + (size_t)4608 * 2048, 2048, 512);
  // 3) fused QKV projection (bf16 out)
  gemm_bt<false><<<dim3(QKVW / 128, 8192 / 128), 256, 0, stream>>>(hidden_bf, bt_qkv, qkv_raw, 8192, QKVW, 2048);
  // 4) RMS-norm + RoPE: q in place, k -> head-major k_f
  norm_rope<<<dim3(8192 * 20 / 4), 256, 0, stream>>>(qkv_raw, cosb, sinb, qnw, knw, k_f);
  // 5) V -> d-major vt (overwrites dead bt_qkv)
  transpose_v<<<dim3(SEQ / 64, HDIM / 64, NB * NKV), 256, 0, stream>>>(qkv_raw, vt);
  // 6) convert+transpose wo
  transpose_w<<<dim3(32, 32), 256, 0, stream>>>(wo, bt_wo, 2048, 2048);
  // 7) causal flash attention + gating (writes g_attn over dead hidden_bf)
  attn_kernel<<<dim3(32, NHEAD, NB), 256, 0, stream>>>(qkv_raw, k_f, vt, g_attn);
  // 8) output projection, fp32 store
  gemm_bt<true><<<dim3(2048 / 128, 8192 / 128), 256, 0, stream>>>(g_attn, bt_wo, out, 8192, 2048, 2048);
}